// Round 6
// baseline (139.332 us; speedup 1.0000x reference)
//
#include <hip/hip_runtime.h>
#include <hip/hip_bf16.h>
#include <math.h>

#define BB 4
#define CC 192
#define HH 56
#define WW 56
#define HWW 3136

typedef __attribute__((ext_vector_type(8))) short short8;
typedef __attribute__((ext_vector_type(4))) float f32x4;

__device__ __forceinline__ unsigned short f2b(float f) {
    __hip_bfloat16 h = __float2bfloat16(f);
    return __builtin_bit_cast(unsigned short, h);
}
__device__ __forceinline__ float b2f(unsigned short u) {
    unsigned int x = ((unsigned int)u) << 16;
    return __builtin_bit_cast(float, x);
}
__device__ __forceinline__ void fma4(float4& a, float w, const float4& x) {
    a.x += w * x.x; a.y += w * x.y; a.z += w * x.z; a.w += w * x.w;
}

// ---------------------------------------------------------------------------
// Kernel 1: transpose x (B,C,H,W) -> xt (B,H*W,C) f32 + split bf16 (xth/xtl)
// ---------------------------------------------------------------------------
__global__ __launch_bounds__(256) void k_transpose(const float* __restrict__ x,
                                                   float* __restrict__ xt,
                                                   unsigned short* __restrict__ xth,
                                                   unsigned short* __restrict__ xtl) {
    __shared__ float tile[32][33];
    int bx = blockIdx.x, by = blockIdx.y, b = blockIdx.z;
    int tx = threadIdx.x, ty = threadIdx.y;
    int p0 = bx * 32, c0 = by * 32;
#pragma unroll
    for (int i = 0; i < 4; i++) {
        int c = c0 + ty + 8 * i;
        tile[ty + 8 * i][tx] = x[(b * CC + c) * HWW + p0 + tx];
    }
    __syncthreads();
#pragma unroll
    for (int i = 0; i < 4; i++) {
        int p = p0 + ty + 8 * i;
        float v = tile[tx][ty + 8 * i];
        size_t o = (size_t)(b * HWW + p) * CC + c0 + tx;
        xt[o] = v;
        unsigned short hi = f2b(v);
        xth[o] = hi;
        xtl[o] = f2b(v - b2f(hi));
    }
}

// ---------------------------------------------------------------------------
// Kernel 2: conv_w (192x384) -> split bf16, K extended to 576:
// k<384 -> cw[o][k]; k in [384,576) -> cw[o][k-192]  (duplicated "out" rows)
// ---------------------------------------------------------------------------
__global__ __launch_bounds__(256) void k_convw(const float* __restrict__ cw,
                                               unsigned short* __restrict__ cwh,
                                               unsigned short* __restrict__ cwl) {
    int i = blockIdx.x * 256 + threadIdx.x;
    if (i < CC * 576) {
        int o = i / 576, k = i % 576;
        int ks = (k >= 384) ? (k - 192) : k;
        float v = cw[o * 384 + ks];
        unsigned short hi = f2b(v);
        cwh[i] = hi;
        cwl[i] = f2b(v - b2f(hi));
    }
}

// ---------------------------------------------------------------------------
// Kernel 3: scores, pair symmetry, channel-half x residue-pair split.
// grid: [0,896) H blocks, [896,1792) W blocks.
// lid encodes (half, rp, b, l0) = 2x2x4x56.  <=1 pair per thread.
// sp layout: [half][b][27][3136] f32 partials.
// ---------------------------------------------------------------------------
__global__ __launch_bounds__(256) void k_scores(const float* __restrict__ xt,
                                                float* __restrict__ sp) {
    __shared__ float Xs[28 * 100];   // 2 classes x 14 rows x 96ch(+4 pad), 11.2KB
    int bid = blockIdx.x, tid = threadIdx.x;
    bool isH = bid < 896;
    int lid = isH ? bid : bid - 896;
    int half = lid & 1;
    int rp = (lid >> 1) & 1;         // residue pair: classes {2rp, 2rp+1}
    int cb = lid >> 2;               // 0..223
    int b = cb / 56, l0 = cb % 56;   // column w (H) or row h (W)
    int r0 = rp * 2;

    const float* src = xt + (size_t)(b * HWW) * CC + half * 96;
    for (int idx = tid; idx < 28 * 24; idx += 256) {
        int t2 = idx / 24, cq = idx % 24;
        int pi = (r0 + t2 / 14) + 4 * (t2 % 14);      // pixel coord along axis
        int pix = isH ? (pi * WW + l0) : (l0 * WW + pi);
        float4 v = *(const float4*)(src + (size_t)pix * CC + cq * 4);
        *(float4*)&Xs[t2 * 100 + cq * 4] = v;
    }
    __syncthreads();

    const float K2 = 0.38490017945975050f;  // 2 / sqrt(27)
    int perCls = isH ? 105 : 91;
    int nI = 2 * perCls;
    if (tid < nI) {
        int cls = tid / perCls, p = tid % perCls;
        int a, bb;
        if (isH) {
            a = (int)((sqrtf((float)(8 * p + 1)) - 1.0f) * 0.5f);
            bb = p - (a * (a + 1)) / 2;
        } else {
            int ap = (int)((sqrtf((float)(8 * p + 1)) - 1.0f) * 0.5f);
            bb = p - (ap * (ap + 1)) / 2;
            a = ap + 1;
        }
        const float* pA = &Xs[(cls * 14 + a) * 100];
        const float* pB = &Xs[(cls * 14 + bb) * 100];
        float s0 = 0.f, s1 = 0.f, s2 = 0.f, s3 = 0.f;
#pragma unroll
        for (int q = 0; q < 24; q++) {
            float4 av = *(const float4*)(pA + q * 4);
            float4 bv = *(const float4*)(pB + q * 4);
            s0 += __builtin_amdgcn_rcpf(__expf(av.x * bv.x * K2) + 1.0f);
            s1 += __builtin_amdgcn_rcpf(__expf(av.y * bv.y * K2) + 1.0f);
            s2 += __builtin_amdgcn_rcpf(__expf(av.z * bv.z * K2) + 1.0f);
            s3 += __builtin_amdgcn_rcpf(__expf(av.w * bv.w * K2) + 1.0f);
        }
        float s = 96.0f - 2.0f * (s0 + s1 + s2 + s3);   // sum tanh
        int r = r0 + cls;
        int sb = (half * BB + b) * 27;
        if (isH) {
            int i1 = a - bb;
            int h1 = r + 4 * a, h2 = r + 4 * bb;
            sp[(sb + i1) * HWW + h1 * WW + l0] = s;
            if (a != bb) sp[(sb + 14 - i1) * HWW + h2 * WW + l0] = s;
        } else {
            int d = a - bb;                        // 1..13
            int w1 = r + 4 * a, w2 = r + 4 * bb;
            sp[(sb + 14 + (d - 1)) * HWW + l0 * WW + w1] = s;
            sp[(sb + 14 + (13 - d)) * HWW + l0 * WW + w2] = s;
        }
    }
}

// ---------------------------------------------------------------------------
// Kernel 4: softmax + weighted accumulation, one launch.
// blocks [0,224): columns -> oHh/oHl; [224,448): rows -> oWh/oWl (split bf16).
// ---------------------------------------------------------------------------
__global__ __launch_bounds__(256) void k_acc(const float* __restrict__ xt,
                                             const float* __restrict__ sp,
                                             unsigned short* __restrict__ oHh,
                                             unsigned short* __restrict__ oHl,
                                             unsigned short* __restrict__ oWh,
                                             unsigned short* __restrict__ oWl) {
    __shared__ float Wt[14 * 56];
    int bid = blockIdx.x, tid = threadIdx.x;
    bool isH = bid < 224;
    int lid = isH ? bid : bid - 224;
    int b = lid / 56, l0 = lid % 56;

    if (tid < 56) {
        int pix = isH ? (tid * WW + l0) : (l0 * WW + tid);
        float sc[27], mx = -1e30f;
#pragma unroll
        for (int s = 0; s < 27; s++) {
            float v = sp[((0 * BB + b) * 27 + s) * HWW + pix] +
                      sp[((1 * BB + b) * 27 + s) * HWW + pix];
            sc[s] = v; mx = fmaxf(mx, v);
        }
        float sum = 0.f;
#pragma unroll
        for (int s = 0; s < 27; s++) { sc[s] = __expf(sc[s] - mx); sum += sc[s]; }
        float inv = __builtin_amdgcn_rcpf(sum);
        if (isH) {
#pragma unroll
            for (int i = 0; i < 14; i++) Wt[i * 56 + tid] = sc[i] * inv;
        } else {
#pragma unroll
            for (int j = 0; j < 13; j++) Wt[j * 56 + tid] = sc[14 + j] * inv;
        }
    }
    __syncthreads();
    if (tid < 192) {
        int r = tid & 3, q = tid >> 2;     // class, channel-quad
        float4 in[14];
#pragma unroll
        for (int t = 0; t < 14; t++) {
            int pix = isH ? ((r + 4 * t) * WW + l0) : (l0 * WW + (r + 4 * t));
            in[t] = *(const float4*)(xt + (size_t)(b * HWW + pix) * CC + q * 4);
        }
        float4 acc[14] = {};
        if (isH) {
#pragma unroll
            for (int i = 0; i < 14; i++)
#pragma unroll
                for (int a = 0; a < 14; a++)
                    fma4(acc[a], Wt[i * 56 + (r + 4 * a)], in[(a - i + 14) % 14]);
        } else {
#pragma unroll
            for (int j = 0; j < 13; j++)
#pragma unroll
                for (int a = 0; a < 14; a++)
                    fma4(acc[a], Wt[j * 56 + (r + 4 * a)], in[(a - j - 1 + 14) % 14]);
        }
        unsigned short* dh = isH ? oHh : oWh;
        unsigned short* dl = isH ? oHl : oWl;
#pragma unroll
        for (int a = 0; a < 14; a++) {
            int pix = isH ? ((r + 4 * a) * WW + l0) : (l0 * WW + (r + 4 * a));
            size_t o = (size_t)(b * HWW + pix) * CC + q * 4;
            ushort4 hi4, lo4;
            hi4.x = f2b(acc[a].x); lo4.x = f2b(acc[a].x - b2f(hi4.x));
            hi4.y = f2b(acc[a].y); lo4.y = f2b(acc[a].y - b2f(hi4.y));
            hi4.z = f2b(acc[a].z); lo4.z = f2b(acc[a].z - b2f(hi4.z));
            hi4.w = f2b(acc[a].w); lo4.w = f2b(acc[a].w - b2f(hi4.w));
            *(ushort4*)(dh + o) = hi4;
            *(ushort4*)(dl + o) = lo4;
        }
    }
}

// ---------------------------------------------------------------------------
// Kernel 5: 1x1 conv, split-bf16 MFMA GEMM, A=[x|oH|oW], M=12544 N=192 K=576
// + bias + BN + exact GELU. Tile 64x64, K-chunk 64, 4 waves.
// ---------------------------------------------------------------------------
__global__ __launch_bounds__(256) void k_conv(const unsigned short* __restrict__ xth,
                                              const unsigned short* __restrict__ xtl,
                                              const unsigned short* __restrict__ oHh,
                                              const unsigned short* __restrict__ oHl,
                                              const unsigned short* __restrict__ oWh,
                                              const unsigned short* __restrict__ oWl,
                                              const unsigned short* __restrict__ cwh,
                                              const unsigned short* __restrict__ cwl,
                                              const float* __restrict__ cb,
                                              const float* __restrict__ gma,
                                              const float* __restrict__ bta,
                                              const float* __restrict__ mea,
                                              const float* __restrict__ var,
                                              float* __restrict__ y) {
    __shared__ unsigned short AB[4 * 64 * 72];   // 36864 B
    unsigned short* Ah = AB;
    unsigned short* Al = AB + 64 * 72;
    unsigned short* Bh = AB + 2 * 64 * 72;
    unsigned short* Bl = AB + 3 * 64 * 72;
    int bm = blockIdx.x * 64, bn = blockIdx.y * 64;
    int tid = threadIdx.x, lane = tid & 63, wv = tid >> 6;

    f32x4 acc[4] = {{0,0,0,0},{0,0,0,0},{0,0,0,0},{0,0,0,0}};

    for (int kc9 = 0; kc9 < 9; kc9++) {
        const unsigned short* sh;
        const unsigned short* sl;
        int coff;
        if (kc9 < 3)      { sh = xth; sl = xtl; coff = kc9 * 64; }
        else if (kc9 < 6) { sh = oHh; sl = oHl; coff = (kc9 - 3) * 64; }
        else              { sh = oWh; sl = oWl; coff = (kc9 - 6) * 64; }
#pragma unroll
        for (int r2 = 0; r2 < 2; r2++) {
            int idx = tid + r2 * 256;
            int m = idx >> 3, kq = idx & 7;
            size_t ao = (size_t)(bm + m) * CC + coff + kq * 8;
            *(short8*)&Ah[m * 72 + kq * 8] = *(const short8*)(sh + ao);
            *(short8*)&Al[m * 72 + kq * 8] = *(const short8*)(sl + ao);
            size_t bo = (size_t)(bn + m) * 576 + kc9 * 64 + kq * 8;
            *(short8*)&Bh[m * 72 + kq * 8] = *(const short8*)(cwh + bo);
            *(short8*)&Bl[m * 72 + kq * 8] = *(const short8*)(cwl + bo);
        }
        __syncthreads();
        int n0 = wv * 16;
        int k8 = lane >> 4;        // 0..3
        int col = lane & 15;
#pragma unroll
        for (int ks = 0; ks < 64; ks += 32) {
            int koff = ks + k8 * 8;
            short8 bfh = *(const short8*)&Bh[(n0 + col) * 72 + koff];
            short8 bfl = *(const short8*)&Bl[(n0 + col) * 72 + koff];
#pragma unroll
            for (int fm = 0; fm < 4; fm++) {
                short8 afh = *(const short8*)&Ah[(fm * 16 + col) * 72 + koff];
                short8 afl = *(const short8*)&Al[(fm * 16 + col) * 72 + koff];
                acc[fm] = __builtin_amdgcn_mfma_f32_16x16x32_bf16(afh, bfh, acc[fm], 0, 0, 0);
                acc[fm] = __builtin_amdgcn_mfma_f32_16x16x32_bf16(afl, bfh, acc[fm], 0, 0, 0);
                acc[fm] = __builtin_amdgcn_mfma_f32_16x16x32_bf16(afh, bfl, acc[fm], 0, 0, 0);
            }
        }
        __syncthreads();
    }

    // Epilogue: LDS transpose for coalesced channel-major stores
    float* Ds = (float*)AB;
    {
        int col = lane & 15, rowq = lane >> 4;
#pragma unroll
        for (int fm = 0; fm < 4; fm++)
#pragma unroll
            for (int rg = 0; rg < 4; rg++)
                Ds[(fm * 16 + rowq * 4 + rg) * 68 + wv * 16 + col] = acc[fm][rg];
    }
    __syncthreads();
    {
        int o = tid >> 2, mq0 = tid & 3;
        int oo = bn + o;
        float bias = cb[oo];
        float inv  = gma[oo] * rsqrtf(var[oo] + 1e-5f);
        float mean = mea[oo], beta = bta[oo];
        int b = bm / HWW, p0 = bm % HWW;
#pragma unroll
        for (int g = 0; g < 4; g++) {
            int mq = mq0 + g * 4;
            float v[4];
#pragma unroll
            for (int j = 0; j < 4; j++) {
                float t = Ds[(mq * 4 + j) * 68 + o] + bias;
                t = (t - mean) * inv + beta;
                v[j] = 0.5f * t * (1.0f + erff(t * 0.70710678118654752f));
            }
            float4 st; st.x = v[0]; st.y = v[1]; st.z = v[2]; st.w = v[3];
            *(float4*)&y[(size_t)(b * CC + oo) * HWW + p0 + mq * 4] = st;
        }
    }
}

// ---------------------------------------------------------------------------
extern "C" void kernel_launch(void* const* d_in, const int* in_sizes, int n_in,
                              void* d_out, int out_size, void* d_ws, size_t ws_size,
                              hipStream_t stream) {
    const float* x   = (const float*)d_in[0];
    const float* cw  = (const float*)d_in[1];
    const float* cb  = (const float*)d_in[2];
    const float* gma = (const float*)d_in[3];
    const float* bta = (const float*)d_in[4];
    const float* mea = (const float*)d_in[5];
    const float* var = (const float*)d_in[6];
    float* out = (float*)d_out;

    float* ws = (float*)d_ws;
    float*          xt   = ws;                                  // 2,408,448 f32
    float*          sp   = ws + 2408448;                        //   677,376 f32
    unsigned short* xth  = (unsigned short*)(ws + 3085824);     // 2,408,448 us
    unsigned short* xtl  = (unsigned short*)(ws + 4290048);
    unsigned short* oHh  = (unsigned short*)(ws + 5494272);
    unsigned short* oHl  = (unsigned short*)(ws + 6698496);
    unsigned short* oWh  = (unsigned short*)(ws + 7902720);
    unsigned short* oWl  = (unsigned short*)(ws + 9106944);
    unsigned short* cwh  = (unsigned short*)(ws + 10311168);    //   110,592 us
    unsigned short* cwl  = (unsigned short*)(ws + 10366464);

    k_transpose<<<dim3(98, 6, 4), dim3(32, 8), 0, stream>>>(x, xt, xth, xtl);
    k_convw<<<432, 256, 0, stream>>>(cw, cwh, cwl);
    k_scores<<<1792, 256, 0, stream>>>(xt, sp);
    k_acc<<<448, 256, 0, stream>>>(xt, sp, oHh, oHl, oWh, oWl);
    k_conv<<<dim3(196, 3), 256, 0, stream>>>(xth, xtl, oHh, oHl, oWh, oWl,
                                             cwh, cwl, cb, gma, bta, mea, var, out);
}

// Round 7
// 132.214 us; speedup vs baseline: 1.0538x; 1.0538x over previous
//
#include <hip/hip_runtime.h>
#include <hip/hip_bf16.h>
#include <math.h>

#define BB 4
#define CC 192
#define HH 56
#define WW 56
#define HWW 3136

typedef __attribute__((ext_vector_type(8))) short short8;
typedef __attribute__((ext_vector_type(4))) float f32x4;

__device__ __forceinline__ unsigned short f2b(float f) {
    __hip_bfloat16 h = __float2bfloat16(f);
    return __builtin_bit_cast(unsigned short, h);
}
__device__ __forceinline__ float b2f(unsigned short u) {
    unsigned int x = ((unsigned int)u) << 16;
    return __builtin_bit_cast(float, x);
}
__device__ __forceinline__ void fma4(float4& a, float w, const float4& x) {
    a.x += w * x.x; a.y += w * x.y; a.z += w * x.z; a.w += w * x.w;
}

// ---------------------------------------------------------------------------
// Kernel 1 (fused): blocks [0,2352): transpose x (B,C,H,W) -> xt (B,HW,C) f32
//                   blocks [2352,2784): conv_w -> split bf16, K extended to 576
// ---------------------------------------------------------------------------
__global__ __launch_bounds__(256) void k_pre(const float* __restrict__ x,
                                             float* __restrict__ xt,
                                             const float* __restrict__ cw,
                                             unsigned short* __restrict__ cwh,
                                             unsigned short* __restrict__ cwl) {
    int tid = threadIdx.x;
    if (blockIdx.x < 2352) {
        __shared__ float tile[32][33];
        int id = blockIdx.x;
        int b = id / 588, rem = id % 588;
        int by = rem / 98, bx = rem % 98;
        int tx = tid & 31, ty = tid >> 5;
        int p0 = bx * 32, c0 = by * 32;
#pragma unroll
        for (int i = 0; i < 4; i++) {
            int c = c0 + ty + 8 * i;
            tile[ty + 8 * i][tx] = x[(b * CC + c) * HWW + p0 + tx];
        }
        __syncthreads();
#pragma unroll
        for (int i = 0; i < 4; i++) {
            int p = p0 + ty + 8 * i;
            xt[(size_t)(b * HWW + p) * CC + c0 + tx] = tile[tx][ty + 8 * i];
        }
    } else {
        int i = (blockIdx.x - 2352) * 256 + tid;
        if (i < CC * 576) {
            int o = i / 576, k = i % 576;
            int ks = (k >= 384) ? (k - 192) : k;
            float v = cw[o * 384 + ks];
            unsigned short hi = f2b(v);
            cwh[i] = hi;
            cwl[i] = f2b(v - b2f(hi));
        }
    }
}

// ---------------------------------------------------------------------------
// Kernel 2: scores, pair symmetry, channel-half x residue-pair split.
// grid: [0,896) H blocks, [896,1792) W blocks.
// sp layout: [half][b][pix][32] (27 slots used, pixel-major for coalesced
// softmax reads).
// ---------------------------------------------------------------------------
__global__ __launch_bounds__(256) void k_scores(const float* __restrict__ xt,
                                                float* __restrict__ sp) {
    __shared__ float Xs[28 * 100];   // 2 classes x 14 rows x 96ch(+4 pad), 11.2KB
    int bid = blockIdx.x, tid = threadIdx.x;
    bool isH = bid < 896;
    int lid = isH ? bid : bid - 896;
    int half = lid & 1;
    int rp = (lid >> 1) & 1;         // residue pair: classes {2rp, 2rp+1}
    int cb = lid >> 2;               // 0..223
    int b = cb / 56, l0 = cb % 56;   // column w (H) or row h (W)
    int r0 = rp * 2;

    const float* src = xt + (size_t)(b * HWW) * CC + half * 96;
    for (int idx = tid; idx < 28 * 24; idx += 256) {
        int t2 = idx / 24, cq = idx % 24;
        int pi = (r0 + t2 / 14) + 4 * (t2 % 14);      // pixel coord along axis
        int pix = isH ? (pi * WW + l0) : (l0 * WW + pi);
        float4 v = *(const float4*)(src + (size_t)pix * CC + cq * 4);
        *(float4*)&Xs[t2 * 100 + cq * 4] = v;
    }
    __syncthreads();

    const float K2 = 0.38490017945975050f;  // 2 / sqrt(27)
    int perCls = isH ? 105 : 91;
    int nI = 2 * perCls;
    if (tid < nI) {
        int cls = tid / perCls, p = tid % perCls;
        int a, bb;
        if (isH) {
            a = (int)((sqrtf((float)(8 * p + 1)) - 1.0f) * 0.5f);
            bb = p - (a * (a + 1)) / 2;
        } else {
            int ap = (int)((sqrtf((float)(8 * p + 1)) - 1.0f) * 0.5f);
            bb = p - (ap * (ap + 1)) / 2;
            a = ap + 1;
        }
        const float* pA = &Xs[(cls * 14 + a) * 100];
        const float* pB = &Xs[(cls * 14 + bb) * 100];
        float s0 = 0.f, s1 = 0.f, s2 = 0.f, s3 = 0.f;
#pragma unroll
        for (int q = 0; q < 24; q++) {
            float4 av = *(const float4*)(pA + q * 4);
            float4 bv = *(const float4*)(pB + q * 4);
            s0 += __builtin_amdgcn_rcpf(__expf(av.x * bv.x * K2) + 1.0f);
            s1 += __builtin_amdgcn_rcpf(__expf(av.y * bv.y * K2) + 1.0f);
            s2 += __builtin_amdgcn_rcpf(__expf(av.z * bv.z * K2) + 1.0f);
            s3 += __builtin_amdgcn_rcpf(__expf(av.w * bv.w * K2) + 1.0f);
        }
        float s = 96.0f - 2.0f * (s0 + s1 + s2 + s3);   // sum tanh
        int r = r0 + cls;
        size_t base = (size_t)(half * BB + b) * HWW;
        if (isH) {
            int i1 = a - bb;
            int h1 = r + 4 * a, h2 = r + 4 * bb;
            sp[(base + h1 * WW + l0) * 32 + i1] = s;
            if (a != bb) sp[(base + h2 * WW + l0) * 32 + (14 - i1)] = s;
        } else {
            int d = a - bb;                        // 1..13
            int w1 = r + 4 * a, w2 = r + 4 * bb;
            sp[(base + l0 * WW + w1) * 32 + 14 + (d - 1)] = s;
            sp[(base + l0 * WW + w2) * 32 + 14 + (13 - d)] = s;
        }
    }
}

// ---------------------------------------------------------------------------
// Kernel 3: softmax + weighted accumulation, one launch, 192 threads.
// blocks [0,224): columns -> oHh/oHl; [224,448): rows -> oWh/oWl (split bf16).
// ---------------------------------------------------------------------------
__global__ __launch_bounds__(192) void k_acc(const float* __restrict__ xt,
                                             const float* __restrict__ sp,
                                             unsigned short* __restrict__ oHh,
                                             unsigned short* __restrict__ oHl,
                                             unsigned short* __restrict__ oWh,
                                             unsigned short* __restrict__ oWl) {
    __shared__ float Wt[14 * 56];
    int bid = blockIdx.x, tid = threadIdx.x;
    bool isH = bid < 224;
    int lid = isH ? bid : bid - 224;
    int b = lid / 56, l0 = lid % 56;

    if (tid < 56) {
        int pix = isH ? (tid * WW + l0) : (l0 * WW + tid);
        const float4* p0 = (const float4*)&sp[((size_t)(0 * BB + b) * HWW + pix) * 32];
        const float4* p1 = (const float4*)&sp[((size_t)(1 * BB + b) * HWW + pix) * 32];
        float sc[28];
#pragma unroll
        for (int j = 0; j < 7; j++) {
            float4 u = p0[j], v = p1[j];
            sc[4 * j + 0] = u.x + v.x; sc[4 * j + 1] = u.y + v.y;
            sc[4 * j + 2] = u.z + v.z; sc[4 * j + 3] = u.w + v.w;
        }
        float mx = -1e30f;
#pragma unroll
        for (int s = 0; s < 27; s++) mx = fmaxf(mx, sc[s]);
        float sum = 0.f;
#pragma unroll
        for (int s = 0; s < 27; s++) { sc[s] = __expf(sc[s] - mx); sum += sc[s]; }
        float inv = __builtin_amdgcn_rcpf(sum);
        if (isH) {
#pragma unroll
            for (int i = 0; i < 14; i++) Wt[i * 56 + tid] = sc[i] * inv;
        } else {
#pragma unroll
            for (int j = 0; j < 13; j++) Wt[j * 56 + tid] = sc[14 + j] * inv;
        }
    }
    __syncthreads();
    {
        int r = tid & 3, q = tid >> 2;     // class, channel-quad
        float4 in[14];
#pragma unroll
        for (int t = 0; t < 14; t++) {
            int pix = isH ? ((r + 4 * t) * WW + l0) : (l0 * WW + (r + 4 * t));
            in[t] = *(const float4*)(xt + (size_t)(b * HWW + pix) * CC + q * 4);
        }
        float4 acc[14] = {};
        if (isH) {
#pragma unroll
            for (int i = 0; i < 14; i++)
#pragma unroll
                for (int a = 0; a < 14; a++)
                    fma4(acc[a], Wt[i * 56 + (r + 4 * a)], in[(a - i + 14) % 14]);
        } else {
#pragma unroll
            for (int j = 0; j < 13; j++)
#pragma unroll
                for (int a = 0; a < 14; a++)
                    fma4(acc[a], Wt[j * 56 + (r + 4 * a)], in[(a - j - 1 + 14) % 14]);
        }
        unsigned short* dh = isH ? oHh : oWh;
        unsigned short* dl = isH ? oHl : oWl;
#pragma unroll
        for (int a = 0; a < 14; a++) {
            int pix = isH ? ((r + 4 * a) * WW + l0) : (l0 * WW + (r + 4 * a));
            size_t o = (size_t)(b * HWW + pix) * CC + q * 4;
            ushort4 hi4, lo4;
            hi4.x = f2b(acc[a].x); lo4.x = f2b(acc[a].x - b2f(hi4.x));
            hi4.y = f2b(acc[a].y); lo4.y = f2b(acc[a].y - b2f(hi4.y));
            hi4.z = f2b(acc[a].z); lo4.z = f2b(acc[a].z - b2f(hi4.z));
            hi4.w = f2b(acc[a].w); lo4.w = f2b(acc[a].w - b2f(hi4.w));
            *(ushort4*)(dh + o) = hi4;
            *(ushort4*)(dl + o) = lo4;
        }
    }
}

// ---------------------------------------------------------------------------
// Kernel 4: 1x1 conv, split-bf16 MFMA GEMM, A=[x|oH|oW], M=12544 N=192 K=576
// + bias + BN + exact GELU. Tile 64x64, K-chunk 64, 4 waves.
// x rows are split hi/lo on the fly from f32 xt; oH/oW rows pre-split.
// ---------------------------------------------------------------------------
__global__ __launch_bounds__(256) void k_conv(const float* __restrict__ xt,
                                              const unsigned short* __restrict__ oHh,
                                              const unsigned short* __restrict__ oHl,
                                              const unsigned short* __restrict__ oWh,
                                              const unsigned short* __restrict__ oWl,
                                              const unsigned short* __restrict__ cwh,
                                              const unsigned short* __restrict__ cwl,
                                              const float* __restrict__ cb,
                                              const float* __restrict__ gma,
                                              const float* __restrict__ bta,
                                              const float* __restrict__ mea,
                                              const float* __restrict__ var,
                                              float* __restrict__ y) {
    __shared__ unsigned short AB[4 * 64 * 72];   // 36864 B
    unsigned short* Ah = AB;
    unsigned short* Al = AB + 64 * 72;
    unsigned short* Bh = AB + 2 * 64 * 72;
    unsigned short* Bl = AB + 3 * 64 * 72;
    int bm = blockIdx.x * 64, bn = blockIdx.y * 64;
    int tid = threadIdx.x, lane = tid & 63, wv = tid >> 6;

    f32x4 acc[4] = {{0,0,0,0},{0,0,0,0},{0,0,0,0},{0,0,0,0}};

    for (int kc9 = 0; kc9 < 9; kc9++) {
#pragma unroll
        for (int r2 = 0; r2 < 2; r2++) {
            int idx = tid + r2 * 256;
            int m = idx >> 3, kq = idx & 7;
            if (kc9 < 3) {
                const float* s = xt + (size_t)(bm + m) * CC + kc9 * 64 + kq * 8;
                float4 v0 = *(const float4*)s;
                float4 v1 = *(const float4*)(s + 4);
                float v[8] = {v0.x, v0.y, v0.z, v0.w, v1.x, v1.y, v1.z, v1.w};
                unsigned short hi[8], lo[8];
#pragma unroll
                for (int e = 0; e < 8; e++) {
                    hi[e] = f2b(v[e]);
                    lo[e] = f2b(v[e] - b2f(hi[e]));
                }
                *(short8*)&Ah[m * 72 + kq * 8] = *(short8*)hi;
                *(short8*)&Al[m * 72 + kq * 8] = *(short8*)lo;
            } else {
                const unsigned short* sh;
                const unsigned short* sl;
                int coff;
                if (kc9 < 6) { sh = oHh; sl = oHl; coff = (kc9 - 3) * 64; }
                else         { sh = oWh; sl = oWl; coff = (kc9 - 6) * 64; }
                size_t ao = (size_t)(bm + m) * CC + coff + kq * 8;
                *(short8*)&Ah[m * 72 + kq * 8] = *(const short8*)(sh + ao);
                *(short8*)&Al[m * 72 + kq * 8] = *(const short8*)(sl + ao);
            }
            size_t bo = (size_t)(bn + m) * 576 + kc9 * 64 + kq * 8;
            *(short8*)&Bh[m * 72 + kq * 8] = *(const short8*)(cwh + bo);
            *(short8*)&Bl[m * 72 + kq * 8] = *(const short8*)(cwl + bo);
        }
        __syncthreads();
        int n0 = wv * 16;
        int k8 = lane >> 4;        // 0..3
        int col = lane & 15;
#pragma unroll
        for (int ks = 0; ks < 64; ks += 32) {
            int koff = ks + k8 * 8;
            short8 bfh = *(const short8*)&Bh[(n0 + col) * 72 + koff];
            short8 bfl = *(const short8*)&Bl[(n0 + col) * 72 + koff];
#pragma unroll
            for (int fm = 0; fm < 4; fm++) {
                short8 afh = *(const short8*)&Ah[(fm * 16 + col) * 72 + koff];
                short8 afl = *(const short8*)&Al[(fm * 16 + col) * 72 + koff];
                acc[fm] = __builtin_amdgcn_mfma_f32_16x16x32_bf16(afh, bfh, acc[fm], 0, 0, 0);
                acc[fm] = __builtin_amdgcn_mfma_f32_16x16x32_bf16(afl, bfh, acc[fm], 0, 0, 0);
                acc[fm] = __builtin_amdgcn_mfma_f32_16x16x32_bf16(afh, bfl, acc[fm], 0, 0, 0);
            }
        }
        __syncthreads();
    }

    // Epilogue: LDS transpose for coalesced channel-major stores
    float* Ds = (float*)AB;
    {
        int col = lane & 15, rowq = lane >> 4;
#pragma unroll
        for (int fm = 0; fm < 4; fm++)
#pragma unroll
            for (int rg = 0; rg < 4; rg++)
                Ds[(fm * 16 + rowq * 4 + rg) * 68 + wv * 16 + col] = acc[fm][rg];
    }
    __syncthreads();
    {
        int o = tid >> 2, mq0 = tid & 3;
        int oo = bn + o;
        float bias = cb[oo];
        float inv  = gma[oo] * rsqrtf(var[oo] + 1e-5f);
        float mean = mea[oo], beta = bta[oo];
        int b = bm / HWW, p0 = bm % HWW;
#pragma unroll
        for (int g = 0; g < 4; g++) {
            int mq = mq0 + g * 4;
            float v[4];
#pragma unroll
            for (int j = 0; j < 4; j++) {
                float t = Ds[(mq * 4 + j) * 68 + o] + bias;
                t = (t - mean) * inv + beta;
                v[j] = 0.5f * t * (1.0f + erff(t * 0.70710678118654752f));
            }
            float4 st; st.x = v[0]; st.y = v[1]; st.z = v[2]; st.w = v[3];
            *(float4*)&y[(size_t)(b * CC + oo) * HWW + p0 + mq * 4] = st;
        }
    }
}

// ---------------------------------------------------------------------------
extern "C" void kernel_launch(void* const* d_in, const int* in_sizes, int n_in,
                              void* d_out, int out_size, void* d_ws, size_t ws_size,
                              hipStream_t stream) {
    const float* x   = (const float*)d_in[0];
    const float* cw  = (const float*)d_in[1];
    const float* cb  = (const float*)d_in[2];
    const float* gma = (const float*)d_in[3];
    const float* bta = (const float*)d_in[4];
    const float* mea = (const float*)d_in[5];
    const float* var = (const float*)d_in[6];
    float* out = (float*)d_out;

    float* ws = (float*)d_ws;
    float*          xt  = ws;                                   // 2,408,448 f32
    float*          sp  = ws + 2408448;                         //   802,816 f32
    unsigned short* oHh = (unsigned short*)(ws + 3211264);      // 2,408,448 us
    unsigned short* oHl = (unsigned short*)(ws + 4415488);
    unsigned short* oWh = (unsigned short*)(ws + 5619712);
    unsigned short* oWl = (unsigned short*)(ws + 6823936);
    unsigned short* cwh = (unsigned short*)(ws + 8028160);      //   110,592 us
    unsigned short* cwl = (unsigned short*)(ws + 8083456);

    k_pre<<<2784, 256, 0, stream>>>(x, xt, cw, cwh, cwl);
    k_scores<<<1792, 256, 0, stream>>>(xt, sp);
    k_acc<<<448, 192, 0, stream>>>(xt, sp, oHh, oHl, oWh, oWl);
    k_conv<<<dim3(196, 3), 256, 0, stream>>>(xt, oHh, oHl, oWh, oWl,
                                             cwh, cwl, cb, gma, bta, mea, var, out);
}